// Round 15
// baseline (120.579 us; speedup 1.0000x reference)
//
#include <hip/hip_runtime.h>
#include <hip/hip_bf16.h>

#define DIM  512
#define FEAT 64
#define BATCH 2048

#define ROWS_PER_BLOCK 1024
#define TILES_PER_WAVE 16   // ROWS_PER_BLOCK / (4 waves * 16 rows)

using bf16x8 = __attribute__((ext_vector_type(8))) short;
using f32x4  = __attribute__((ext_vector_type(4))) float;

typedef __attribute__((address_space(3))) float lds_f;
typedef __attribute__((address_space(1))) const float glb_f;

__device__ inline short f2bf(float f) {
    unsigned int u = __float_as_uint(f);
    u += 0x7fffu + ((u >> 16) & 1u);
    return (short)(u >> 16);
}

__device__ inline bf16x8 cvt8(float4 a, float4 b) {
    bf16x8 r;
    r[0] = f2bf(a.x); r[1] = f2bf(a.y); r[2] = f2bf(a.z); r[3] = f2bf(a.w);
    r[4] = f2bf(b.x); r[5] = f2bf(b.y); r[6] = f2bf(b.z); r[7] = f2bf(b.w);
    return r;
}

// R9 grid/walk + R14 store-side bias (LDS exactly 32KB) + NORMAL dense stores
// (the single experiment: L2 write aggregation vs NT HBM-direct).
// arg2=3: VGPR cap ~85, kernel needs ~52 (R9-verified, no spill).
__global__ __launch_bounds__(256, 3)
void split_linear_kernel(const float* __restrict__ x,
                         const float* __restrict__ W,
                         const float* __restrict__ bias,
                         float* __restrict__ out)
{
    // x staging AND out-transpose share slots: [wave][slot][16 rows][16 chunks],
    // 16B-chunk XOR(row&7) swizzle on both paths (R8/R9-verified). 32768 B exactly.
    __shared__ float xlds[4][2][1024];

    // chunked XCD swizzle, d fastest (R9): each XCD owns a contiguous d-range.
    const int id    = blockIdx.x;          // 0..1023
    const int xcd   = id & 7;
    const int chunk = id >> 3;             // 0..127
    const int nid   = xcd * 128 + chunk;   // 0..1023
    const int d     = nid & (DIM - 1);
    const int b0    = (nid >> 9) * ROWS_PER_BLOCK;

    const int tid  = threadIdx.x;
    const int wave = tid >> 6;
    const int lane = tid & 63;
    const int lr   = lane & 15;   // A-row (g) / B-col (batch row) / store chunk
    const int lk   = lane >> 4;   // k-group

    // ---- W fragments in registers ----
    bf16x8 wf[2][4];
#pragma unroll
    for (int mt = 0; mt < 4; ++mt) {
        const float* wrow = W + ((size_t)d * FEAT + mt * 16 + lr) * FEAT + lk * 8;
#pragma unroll
        for (int ks = 0; ks < 2; ++ks) {
            float4 w0 = *(const float4*)(wrow + ks * 32);
            float4 w1 = *(const float4*)(wrow + ks * 32 + 4);
            wf[ks][mt] = cvt8(w0, w1);
        }
    }

    // ---- store-side bias (R14-verified): lane adds bias[d][cc*4..+3], cc = lr ----
    const f32x4 bstore = *(const f32x4*)(bias + (size_t)d * FEAT + lr * 4);

    // ---- async dense stage: 4 instrs, each 4 rows x 256B fully covered ----
    auto stage = [&](int slot, int tt) {
#pragma unroll
        for (int i = 0; i < 4; ++i) {
            const int r = i * 4 + (lane >> 4);
            const int c = (lane & 15) ^ (r & 7);   // pre-swizzled source chunk
            const float* gp = x + ((size_t)(b0 + tt * 16 + r) * DIM + d) * FEAT + c * 4;
            __builtin_amdgcn_global_load_lds((glb_f*)gp,
                                             (lds_f*)&xlds[wave][slot][i * 256],
                                             16, 0, 0);
        }
    };

    stage(0, wave);            // tile 0
    stage(1, 4 + wave);        // tile 1

    for (int t = 0; t < TILES_PER_WAVE; ++t) {
        const int s = t & 1;
        // counted vmcnt (R9-verified): steady outstanding (old->new):
        // st(t-2),stage(t),st(t-1),stage(t+1)=16 -> keep newest 8; edges keep 4.
        if (t == 0 || t == TILES_PER_WAVE - 1)
            asm volatile("s_waitcnt vmcnt(4)" ::: "memory");
        else
            asm volatile("s_waitcnt vmcnt(8)" ::: "memory");
        __builtin_amdgcn_sched_barrier(0);

        float* sl = &xlds[wave][s][0];
        float4 p0a = *(const float4*)&sl[lr * 64 + (((lk * 2 + 0) ^ (lr & 7)) << 2)];
        float4 p0b = *(const float4*)&sl[lr * 64 + (((lk * 2 + 1) ^ (lr & 7)) << 2)];
        float4 p1a = *(const float4*)&sl[lr * 64 + (((8 + lk * 2 + 0) ^ (lr & 7)) << 2)];
        float4 p1b = *(const float4*)&sl[lr * 64 + (((8 + lk * 2 + 1) ^ (lr & 7)) << 2)];

        bf16x8 af0 = cvt8(p0a, p0b);   // ks = 0
        bf16x8 af1 = cvt8(p1a, p1b);   // ks = 1

        f32x4 acc[4] = {{0.f,0.f,0.f,0.f},{0.f,0.f,0.f,0.f},
                        {0.f,0.f,0.f,0.f},{0.f,0.f,0.f,0.f}};
#pragma unroll
        for (int mt = 0; mt < 4; ++mt)
            acc[mt] = __builtin_amdgcn_mfma_f32_16x16x32_bf16(wf[0][mt], af0, acc[mt], 0, 0, 0);
#pragma unroll
        for (int mt = 0; mt < 4; ++mt)
            acc[mt] = __builtin_amdgcn_mfma_f32_16x16x32_bf16(wf[1][mt], af1, acc[mt], 0, 0, 0);

        // ---- transpose INTO the just-consumed slot (wave-private, DS in-order) ----
#pragma unroll
        for (int mt = 0; mt < 4; ++mt) {
            const int c  = mt * 4 + lk;
            const int pc = c ^ (lr & 7);           // same swizzle as stage
            *(f32x4*)&sl[lr * 64 + pc * 4] = acc[mt];
        }

        // ---- dense NORMAL store-back + bias: instr j covers rows j*4..+3, 256B/row.
        //      Full lines aggregate in L2 and drain in large write bursts (the test). ----
        const int orow0 = b0 + (t * 4 + wave) * 16;
#pragma unroll
        for (int j = 0; j < 4; ++j) {
            const int rr  = j * 4 + (lane >> 4);
            const int cc  = lane & 15;
            const int pc2 = cc ^ (rr & 7);
            f32x4 v = *(const f32x4*)&sl[rr * 64 + pc2 * 4];
            v += bstore;   // bias[d][cc*4..+3], row-independent
            *(f32x4*)(out + ((size_t)(orow0 + rr) * DIM + d) * FEAT + cc * 4) = v;
        }
        __builtin_amdgcn_sched_barrier(0);   // pin the re-stage below the stores

        if (t + 2 < TILES_PER_WAVE)
            stage(s, (t + 2) * 4 + wave);    // reuse slot s (DMA lands after ds_reads)
    }
}

extern "C" void kernel_launch(void* const* d_in, const int* in_sizes, int n_in,
                              void* d_out, int out_size, void* d_ws, size_t ws_size,
                              hipStream_t stream) {
    const float* x    = (const float*)d_in[0];
    const float* W    = (const float*)d_in[1];
    const float* bias = (const float*)d_in[2];
    float* out        = (float*)d_out;

    dim3 grid(DIM * (BATCH / ROWS_PER_BLOCK), 1, 1);  // 1024 blocks (R9 grid)
    dim3 block(256, 1, 1);
    split_linear_kernel<<<grid, block, 0, stream>>>(x, W, bias, out);
}

// Round 16
// 103.921 us; speedup vs baseline: 1.1603x; 1.1603x over previous
//
#include <hip/hip_runtime.h>
#include <hip/hip_bf16.h>

#define DIM  512
#define FEAT 64
#define BATCH 2048

#define ROWS_PER_BLOCK 1024
#define TILES_PER_WAVE 16   // ROWS_PER_BLOCK / (4 waves * 16 rows)

using bf16x8 = __attribute__((ext_vector_type(8))) short;
using f32x4  = __attribute__((ext_vector_type(4))) float;

typedef __attribute__((address_space(3))) float lds_f;
typedef __attribute__((address_space(1))) const float glb_f;

__device__ inline short f2bf(float f) {
    unsigned int u = __float_as_uint(f);
    u += 0x7fffu + ((u >> 16) & 1u);
    return (short)(u >> 16);
}

__device__ inline bf16x8 cvt8(float4 a, float4 b) {
    bf16x8 r;
    r[0] = f2bf(a.x); r[1] = f2bf(a.y); r[2] = f2bf(a.z); r[3] = f2bf(a.w);
    r[4] = f2bf(b.x); r[5] = f2bf(b.y); r[6] = f2bf(b.z); r[7] = f2bf(b.w);
    return r;
}

// FINAL (R9, 104 µs): bf16 MFMA core, register W, dense global_load_lds staging,
// shared stage/transpose LDS slots (XOR-swizzled both sides), counted vmcnt,
// dense NT stores, XCD-chunked d-major grid. ~3.9 TB/s HBM-side sustained.
// arg2=3: VGPR cap ~85, kernel needs ~52 (verified no spill).
__global__ __launch_bounds__(256, 3)
void split_linear_kernel(const float* __restrict__ x,
                         const float* __restrict__ W,
                         const float* __restrict__ bias,
                         float* __restrict__ out)
{
    // x staging AND out-transpose share slots: [wave][slot][16 rows][16 chunks]
    // 16B-chunk XOR(row&7) swizzle on both paths (R8/R9-verified).
    __shared__ float xlds[4][2][1024];
    __shared__ float blds[FEAT];

    // chunked XCD swizzle, d fastest: co-resident blocks on a CU get CONSECUTIVE d
    const int id    = blockIdx.x;          // 0..1023
    const int xcd   = id & 7;
    const int chunk = id >> 3;             // 0..127
    const int nid   = xcd * 128 + chunk;   // 0..1023
    const int d     = nid & (DIM - 1);
    const int b0    = (nid >> 9) * ROWS_PER_BLOCK;

    const int tid  = threadIdx.x;
    const int wave = tid >> 6;
    const int lane = tid & 63;
    const int lr   = lane & 15;   // A-row (g) / B-col (batch row)
    const int lk   = lane >> 4;   // k-group / D row-quad

    if (tid < FEAT) blds[tid] = bias[(size_t)d * FEAT + tid];
    __syncthreads();

    // ---- W fragments in registers ----
    bf16x8 wf[2][4];
#pragma unroll
    for (int mt = 0; mt < 4; ++mt) {
        const float* wrow = W + ((size_t)d * FEAT + mt * 16 + lr) * FEAT + lk * 8;
#pragma unroll
        for (int ks = 0; ks < 2; ++ks) {
            float4 w0 = *(const float4*)(wrow + ks * 32);
            float4 w1 = *(const float4*)(wrow + ks * 32 + 4);
            wf[ks][mt] = cvt8(w0, w1);
        }
    }

    // ---- async dense stage: 4 instrs, each 4 rows x 256B fully covered ----
    auto stage = [&](int slot, int tt) {
#pragma unroll
        for (int i = 0; i < 4; ++i) {
            const int r = i * 4 + (lane >> 4);
            const int c = (lane & 15) ^ (r & 7);   // pre-swizzled source chunk
            const float* gp = x + ((size_t)(b0 + tt * 16 + r) * DIM + d) * FEAT + c * 4;
            __builtin_amdgcn_global_load_lds((glb_f*)gp,
                                             (lds_f*)&xlds[wave][slot][i * 256],
                                             16, 0, 0);
        }
    };

    stage(0, wave);            // tile 0
    stage(1, 4 + wave);        // tile 1

    for (int t = 0; t < TILES_PER_WAVE; ++t) {
        const int s = t & 1;
        // in-order vmcnt retirement: wait until only the newest N remain.
        // steady outstanding (oldest->newest): st(t-2),stage(t),st(t-1),stage(t+1) = 16
        // -> vmcnt(8) retires st(t-2)+stage(t). t=0: [stage0,stage1] -> vmcnt(4).
        // t=last: [st(t-2),stage(t),st(t-1)] -> vmcnt(4).
        if (t == 0 || t == TILES_PER_WAVE - 1)
            asm volatile("s_waitcnt vmcnt(4)" ::: "memory");
        else
            asm volatile("s_waitcnt vmcnt(8)" ::: "memory");
        __builtin_amdgcn_sched_barrier(0);

        float* sl = &xlds[wave][s][0];
        float4 p0a = *(const float4*)&sl[lr * 64 + (((lk * 2 + 0) ^ (lr & 7)) << 2)];
        float4 p0b = *(const float4*)&sl[lr * 64 + (((lk * 2 + 1) ^ (lr & 7)) << 2)];
        float4 p1a = *(const float4*)&sl[lr * 64 + (((8 + lk * 2 + 0) ^ (lr & 7)) << 2)];
        float4 p1b = *(const float4*)&sl[lr * 64 + (((8 + lk * 2 + 1) ^ (lr & 7)) << 2)];

        bf16x8 af0 = cvt8(p0a, p0b);   // ks = 0
        bf16x8 af1 = cvt8(p1a, p1b);   // ks = 1

        f32x4 acc[4];
#pragma unroll
        for (int mt = 0; mt < 4; ++mt)
            acc[mt] = *(const f32x4*)&blds[mt * 16 + lk * 4];
#pragma unroll
        for (int mt = 0; mt < 4; ++mt)
            acc[mt] = __builtin_amdgcn_mfma_f32_16x16x32_bf16(wf[0][mt], af0, acc[mt], 0, 0, 0);
#pragma unroll
        for (int mt = 0; mt < 4; ++mt)
            acc[mt] = __builtin_amdgcn_mfma_f32_16x16x32_bf16(wf[1][mt], af1, acc[mt], 0, 0, 0);

        // ---- transpose INTO the just-consumed slot (per-wave DS ops are in-order;
        //      fragment ds_reads above already completed via lgkm before cvt8) ----
        // lane (lr,lk), mt holds out[row lr][g = mt*16+lk*4 ..+3] -> chunk c = mt*4+lk
#pragma unroll
        for (int mt = 0; mt < 4; ++mt) {
            const int c  = mt * 4 + lk;
            const int pc = c ^ (lr & 7);           // same swizzle as stage
            *(f32x4*)&sl[lr * 64 + pc * 4] = acc[mt];
        }

        // ---- dense NT store-back: instr j covers rows j*4..+3, full 256B per row ----
        const int orow0 = b0 + (t * 4 + wave) * 16;
#pragma unroll
        for (int j = 0; j < 4; ++j) {
            const int rr  = j * 4 + (lane >> 4);
            const int cc  = lane & 15;
            const int pc2 = cc ^ (rr & 7);
            f32x4 v = *(const f32x4*)&sl[rr * 64 + pc2 * 4];
            __builtin_nontemporal_store(v,
                (f32x4*)(out + ((size_t)(orow0 + rr) * DIM + d) * FEAT + cc * 4));
        }
        __builtin_amdgcn_sched_barrier(0);   // pin the re-stage below the stores

        if (t + 2 < TILES_PER_WAVE)
            stage(s, (t + 2) * 4 + wave);    // reuse slot s (DMA lands after ds_reads)
    }
}

extern "C" void kernel_launch(void* const* d_in, const int* in_sizes, int n_in,
                              void* d_out, int out_size, void* d_ws, size_t ws_size,
                              hipStream_t stream) {
    const float* x    = (const float*)d_in[0];
    const float* W    = (const float*)d_in[1];
    const float* bias = (const float*)d_in[2];
    float* out        = (float*)d_out;

    dim3 grid(DIM * (BATCH / ROWS_PER_BLOCK), 1, 1);  // 1024 blocks = 4/CU, one generation
    dim3 block(256, 1, 1);
    split_linear_kernel<<<grid, block, 0, stream>>>(x, W, bias, out);
}